// Round 2
// baseline (41.551 us; speedup 1.0000x reference)
//
#include <hip/hip_runtime.h>
#include <math.h>

// Forward kinematics as an associative scan over affine pairs (M, p):
//   elem_j = (R_j, l_j * R_j[:,2]);  (M1,p1) ⊗ (M2,p2) = (M1*M2, p1 + M1*p2)
// Output_i = p-component of inclusive prefix up to i.

#define TPB 256          // threads per block (phases 1/3)
#define EPT 4            // elements per thread
#define EPB (TPB * EPT)  // 1024 elements per block

struct Xf {
    float m[9];  // row-major 3x3
    float p[3];
};

__device__ __forceinline__ void xf_identity(Xf& x) {
    x.m[0] = 1.f; x.m[1] = 0.f; x.m[2] = 0.f;
    x.m[3] = 0.f; x.m[4] = 1.f; x.m[5] = 0.f;
    x.m[6] = 0.f; x.m[7] = 0.f; x.m[8] = 1.f;
    x.p[0] = 0.f; x.p[1] = 0.f; x.p[2] = 0.f;
}

// out = A ⊗ B  (A is the earlier prefix)
__device__ __forceinline__ Xf xf_comb(const Xf& A, const Xf& B) {
    Xf o;
#pragma unroll
    for (int r = 0; r < 3; ++r) {
        const float a0 = A.m[r * 3 + 0], a1 = A.m[r * 3 + 1], a2 = A.m[r * 3 + 2];
#pragma unroll
        for (int c = 0; c < 3; ++c) {
            o.m[r * 3 + c] = a0 * B.m[0 * 3 + c] + a1 * B.m[1 * 3 + c] + a2 * B.m[2 * 3 + c];
        }
        o.p[r] = A.p[r] + a0 * B.p[0] + a1 * B.p[1] + a2 * B.p[2];
    }
    return o;
}

// a = a ⊗ elem(theta=(ax,ay,az), l).  R = Rz@Ry@Rx (ZYX Euler).
// ACCURATE sincosf (ocml, ~1ulp): the fast __sincosf random-walked to ~2.3%
// end-effector error over 1M chained rotations — above the 2% threshold.
__device__ __forceinline__ void xf_fold(Xf& a, float ax, float ay, float az, float l) {
    float sx, cx, sy, cy, sz, cz;
    sincosf(ax, &sx, &cx);
    sincosf(ay, &sy, &cy);
    sincosf(az, &sz, &cz);
    const float sysx = sy * sx, sycx = sy * cx;
    const float r00 = cz * cy;
    const float r01 = cz * sysx - sz * cx;
    const float r02 = sz * sx + cz * sycx;
    const float r10 = sz * cy;
    const float r11 = cz * cx + sz * sysx;
    const float r12 = sz * sycx - cz * sx;
    const float r20 = -sy;
    const float r21 = cy * sx;
    const float r22 = cy * cx;
    const float t0 = l * r02, t1 = l * r12, t2 = l * r22;
    // p += M @ t   (uses old M)
    const float p0 = a.p[0] + a.m[0] * t0 + a.m[1] * t1 + a.m[2] * t2;
    const float p1 = a.p[1] + a.m[3] * t0 + a.m[4] * t1 + a.m[5] * t2;
    const float p2 = a.p[2] + a.m[6] * t0 + a.m[7] * t1 + a.m[8] * t2;
    // M = M @ R
    const float n0 = a.m[0] * r00 + a.m[1] * r10 + a.m[2] * r20;
    const float n1 = a.m[0] * r01 + a.m[1] * r11 + a.m[2] * r21;
    const float n2 = a.m[0] * r02 + a.m[1] * r12 + a.m[2] * r22;
    const float n3 = a.m[3] * r00 + a.m[4] * r10 + a.m[5] * r20;
    const float n4 = a.m[3] * r01 + a.m[4] * r11 + a.m[5] * r21;
    const float n5 = a.m[3] * r02 + a.m[4] * r12 + a.m[5] * r22;
    const float n6 = a.m[6] * r00 + a.m[7] * r10 + a.m[8] * r20;
    const float n7 = a.m[6] * r01 + a.m[7] * r11 + a.m[8] * r21;
    const float n8 = a.m[6] * r02 + a.m[7] * r12 + a.m[8] * r22;
    a.m[0] = n0; a.m[1] = n1; a.m[2] = n2;
    a.m[3] = n3; a.m[4] = n4; a.m[5] = n5;
    a.m[6] = n6; a.m[7] = n7; a.m[8] = n8;
    a.p[0] = p0; a.p[1] = p1; a.p[2] = p2;
}

// ---------------- Phase 1: per-block aggregates ----------------
__global__ void __launch_bounds__(TPB) fk_phase1(const float* __restrict__ ll,
                                                 const float* __restrict__ th,
                                                 Xf* __restrict__ agg, int n) {
    __shared__ Xf sh[TPB];
    const int t = threadIdx.x;
    const long long j0 = (long long)blockIdx.x * EPB + (long long)t * EPT;

    Xf a;
    xf_identity(a);
    if (j0 + EPT <= n) {
        const float4* th4 = (const float4*)(th + 3 * j0);
        const float4 A = th4[0], B = th4[1], C = th4[2];
        const float4 L = *(const float4*)(ll + j0);
        xf_fold(a, A.x, A.y, A.z, L.x);
        xf_fold(a, A.w, B.x, B.y, L.y);
        xf_fold(a, B.z, B.w, C.x, L.z);
        xf_fold(a, C.y, C.z, C.w, L.w);
    } else {
#pragma unroll
        for (int e = 0; e < EPT; ++e) {
            const long long j = j0 + e;
            if (j < n) xf_fold(a, th[3 * j + 0], th[3 * j + 1], th[3 * j + 2], ll[j]);
        }
    }

    sh[t] = a;
    __syncthreads();
    for (int off = 1; off < TPB; off <<= 1) {
        Xf b;
        const bool act = (t >= off);
        if (act) b = sh[t - off];
        __syncthreads();
        if (act) { a = xf_comb(b, a); sh[t] = a; }
        __syncthreads();
    }
    if (t == TPB - 1) agg[blockIdx.x] = a;  // block inclusive aggregate
}

// ---------------- Phase 2: scan block aggregates (one block) ----------------
__global__ void fk_phase2(Xf* __restrict__ agg, Xf* __restrict__ pfx, int nb) {
    __shared__ Xf sh[1024];
    const int t = threadIdx.x;
    Xf a;
    if (t < nb) a = agg[t]; else xf_identity(a);

    sh[t] = a;
    __syncthreads();
    for (int off = 1; off < (int)blockDim.x; off <<= 1) {
        Xf b;
        const bool act = (t >= off);
        if (act) b = sh[t - off];
        __syncthreads();
        if (act) { a = xf_comb(b, a); sh[t] = a; }
        __syncthreads();
    }
    // exclusive prefix for block t
    Xf ex;
    if (t == 0) xf_identity(ex); else ex = sh[t - 1];
    if (t < nb) pfx[t] = ex;
}

// ---------------- Phase 3: recompute local scans, apply prefixes, write out ----------------
__global__ void __launch_bounds__(TPB) fk_phase3(const float* __restrict__ ll,
                                                 const float* __restrict__ th,
                                                 const Xf* __restrict__ pfx,
                                                 float* __restrict__ out, int n) {
    __shared__ Xf sh[TPB];
    const int t = threadIdx.x;
    const long long j0 = (long long)blockIdx.x * EPB + (long long)t * EPT;

    Xf a;
    xf_identity(a);
    float pe[EPT][3];
    const bool full = (j0 + EPT <= n);
    if (full) {
        const float4* th4 = (const float4*)(th + 3 * j0);
        const float4 A = th4[0], B = th4[1], C = th4[2];
        const float4 L = *(const float4*)(ll + j0);
        xf_fold(a, A.x, A.y, A.z, L.x);
        pe[0][0] = a.p[0]; pe[0][1] = a.p[1]; pe[0][2] = a.p[2];
        xf_fold(a, A.w, B.x, B.y, L.y);
        pe[1][0] = a.p[0]; pe[1][1] = a.p[1]; pe[1][2] = a.p[2];
        xf_fold(a, B.z, B.w, C.x, L.z);
        pe[2][0] = a.p[0]; pe[2][1] = a.p[1]; pe[2][2] = a.p[2];
        xf_fold(a, C.y, C.z, C.w, L.w);
        pe[3][0] = a.p[0]; pe[3][1] = a.p[1]; pe[3][2] = a.p[2];
    } else {
#pragma unroll
        for (int e = 0; e < EPT; ++e) {
            const long long j = j0 + e;
            if (j < n) xf_fold(a, th[3 * j + 0], th[3 * j + 1], th[3 * j + 2], ll[j]);
            pe[e][0] = a.p[0]; pe[e][1] = a.p[1]; pe[e][2] = a.p[2];
        }
    }

    // block scan of thread aggregates -> thread-exclusive prefix
    sh[t] = a;
    __syncthreads();
    for (int off = 1; off < TPB; off <<= 1) {
        Xf b;
        const bool act = (t >= off);
        if (act) b = sh[t - off];
        __syncthreads();
        if (act) { a = xf_comb(b, a); sh[t] = a; }
        __syncthreads();
    }
    Xf ex;
    if (t == 0) xf_identity(ex); else ex = sh[t - 1];

    const Xf G = pfx[blockIdx.x];       // global exclusive prefix of this block
    const Xf T = xf_comb(G, ex);        // total exclusive prefix for this thread

    if (full) {
        float o[EPT * 3];
#pragma unroll
        for (int e = 0; e < EPT; ++e) {
            const float q0 = pe[e][0], q1 = pe[e][1], q2 = pe[e][2];
            o[e * 3 + 0] = T.p[0] + T.m[0] * q0 + T.m[1] * q1 + T.m[2] * q2;
            o[e * 3 + 1] = T.p[1] + T.m[3] * q0 + T.m[4] * q1 + T.m[5] * q2;
            o[e * 3 + 2] = T.p[2] + T.m[6] * q0 + T.m[7] * q1 + T.m[8] * q2;
        }
        float4* o4 = (float4*)(out + 3 * j0);
        o4[0] = make_float4(o[0], o[1], o[2], o[3]);
        o4[1] = make_float4(o[4], o[5], o[6], o[7]);
        o4[2] = make_float4(o[8], o[9], o[10], o[11]);
    } else {
#pragma unroll
        for (int e = 0; e < EPT; ++e) {
            const long long j = j0 + e;
            if (j < n) {
                const float q0 = pe[e][0], q1 = pe[e][1], q2 = pe[e][2];
                out[3 * j + 0] = T.p[0] + T.m[0] * q0 + T.m[1] * q1 + T.m[2] * q2;
                out[3 * j + 1] = T.p[1] + T.m[3] * q0 + T.m[4] * q1 + T.m[5] * q2;
                out[3 * j + 2] = T.p[2] + T.m[6] * q0 + T.m[7] * q1 + T.m[8] * q2;
            }
        }
    }
}

extern "C" void kernel_launch(void* const* d_in, const int* in_sizes, int n_in,
                              void* d_out, int out_size, void* d_ws, size_t ws_size,
                              hipStream_t stream) {
    const float* ll = (const float*)d_in[0];   // link_lengths [N]
    const float* th = (const float*)d_in[1];   // theta [N,3]
    float* out = (float*)d_out;                // [N,3] f32
    const int n = in_sizes[0];

    int nb = (n + EPB - 1) / EPB;              // 1024 for N = 2^20
    if (nb > 1024) nb = 1024;                  // (problem size is fixed at 2^20)

    Xf* agg = (Xf*)d_ws;
    Xf* pfx = agg + nb;

    fk_phase1<<<nb, TPB, 0, stream>>>(ll, th, agg, n);
    fk_phase2<<<1, nb, 0, stream>>>(agg, pfx, nb);
    fk_phase3<<<nb, TPB, 0, stream>>>(ll, th, pfx, out, n);
}